// Round 12
// baseline (745.265 us; speedup 1.0000x reference)
//
#include <hip/hip_runtime.h>
#include <hip/hip_bf16.h>

typedef __hip_bfloat16 bf16;
using short8 = __attribute__((ext_vector_type(8))) short;
using f32x4  = __attribute__((ext_vector_type(4))) float;
using f32x2  = __attribute__((ext_vector_type(2))) float;

#define MFMA16(a,b,c) __builtin_amdgcn_mfma_f32_16x16x32_bf16((a),(b),(c),0,0,0)
#define MAXBUCK 4096   // dst>>5 bins: supports N <= 131072
#define SB 72          // LDS stride (bf16 shorts) for S rows (144B, 16B-aligned)
#define MSTR 72        // LDS stride (bf16) for m rows
#define SRCCAP 1024    // staged src indices per bucket (mean 512, 22 sigma headroom)
#define CHK 8192       // edges per sort chunk (391 chunks -> csort fills the GPU; R6-proven)
#define MAXNC 512      // bsort2 parallel-scan capacity (NC = ceil(E/CHK) = 391)
#define BCAP 2816      // bsort2 staging cap (bin mean 1024, sd 32 -> 56 sigma)

__device__ __forceinline__ float b2f(bf16 v){ return __bfloat162float(v); }
__device__ __forceinline__ bf16  f2b(float v){ return __float2bfloat16(v); }
__device__ __forceinline__ float sigmf(float x){ return 1.f/(1.f+__expf(-x)); }
__device__ __forceinline__ float tanhfast(float x){
  x = fminf(fmaxf(x,-15.f),15.f);
  float e = __expf(2.f*x);
  return (e-1.f)/(e+1.f);
}
__device__ __forceinline__ short8 ld_frag(const bf16* p){
  return *reinterpret_cast<const short8*>(p);
}
__device__ __forceinline__ short f2bits(float f){
  unsigned u = __builtin_bit_cast(unsigned, f);
  unsigned r = (u + 0x7FFFu + ((u>>16)&1u)) >> 16;
  return (short)r;
}
__device__ __forceinline__ f32x2 pk_add(f32x2 a, f32x2 b){
  f32x2 d;
  asm("v_pk_add_f32 %0, %1, %2" : "=v"(d) : "v"(a), "v"(b));
  return d;
}
__device__ __forceinline__ unsigned cvtpk_bf16(float lo, float hi){
  unsigned r;
  asm("v_cvt_pk_bf16_f32 %0, %1, %2" : "=v"(r) : "v"(lo), "v"(hi));
  return r;
}

// ---------------- fp8 e4m3 helpers (pure inline asm, gfx950) ----
__device__ __forceinline__ f32x2 cvt8lo(unsigned w){
  f32x2 r;
  asm("v_cvt_pk_f32_fp8 %0, %1" : "=v"(r) : "v"(w));
  return r;
}
__device__ __forceinline__ f32x2 cvt8hi(unsigned w){
  return cvt8lo(w >> 16);
}
__device__ __forceinline__ unsigned short f32pair_to_fp8(float a, float b){
  unsigned r = 0;
  asm("v_cvt_pk_fp8_f32 %0, %1, %2" : "+v"(r) : "v"(a), "v"(b));
  return (unsigned short)(r & 0xffffu);
}

// ---------------- dtype sniff + workspace zeroing ----------------
// block 0: sniff dtype of x; block 1: zero bkt_cnt; block 2: zero sentinels + gatedG.
__global__ void k_sniff(const unsigned int* __restrict__ x, int* __restrict__ flag,
      int* __restrict__ bkt_cnt, int nb,
      int* __restrict__ s0, int* __restrict__ s1,
      int* __restrict__ s2, int* __restrict__ s3,
      float* __restrict__ gatedG, int ng12){
  int t = threadIdx.x;
  if (blockIdx.x == 1){
    for (int i=t;i<nb;i+=256) bkt_cnt[i]=0;
    return;
  }
  if (blockIdx.x == 2){
    if (t<32){ s0[t]=0; s1[t]=0; }
    if (t<16){ s2[t]=0; s3[t]=0; }
    for (int i=t;i<ng12;i+=256) gatedG[i]=0.f;
    return;
  }
  int good = 0;
  for (int i=t; i<4096; i+=256){
    unsigned w = x[i];
    unsigned e = (w>>23)&0xFFu;
    unsigned m = w & 0x7FFFFFFFu;
    if ((e>=100u && e<=150u) || m==0u) good++;
  }
  __shared__ int sm[256];
  sm[t]=good; __syncthreads();
  if (t==0){ int s=0; for (int k=0;k<256;k++) s+=sm[k]; *flag = (s>2048)?1:0; }
}

struct PtrPack { const void* p[17]; };

#define CAN_X     0
#define CAN_L0W   1500032
#define CAN_L0B   1500992
#define CAN_EE    1501056
#define CAN_CB    1521536
#define CAN_WIH   1521600
#define CAN_WHH   1533888
#define CAN_BIH   1546176
#define CAN_BHH   1546368
#define CAN_IW1   1546560
#define CAN_IB1   1554752
#define CAN_IW2   1554816
#define CAN_IB2   1555584
#define CAN_JW1   1555648
#define CAN_JB1   1559744
#define CAN_JW2   1559808
#define CAN_JB2   1560576
#define CAN_TOT   1560640

__global__ void k_canon(PtrPack pk, const int* __restrict__ flag, bf16* __restrict__ dst){
  static const int offs[17] = {CAN_X,CAN_L0W,CAN_L0B,CAN_EE,CAN_CB,CAN_WIH,CAN_WHH,
    CAN_BIH,CAN_BHH,CAN_IW1,CAN_IB1,CAN_IW2,CAN_IB2,CAN_JW1,CAN_JB1,CAN_JW2,CAN_JB2};
  static const int szs[17]  = {1500000,960,64,20480,64,12288,12288,192,192,8192,64,768,12,4096,64,768,12};
  int t = blockIdx.x*256+threadIdx.x;
  if (t >= CAN_TOT) return;
  int s = 0;
  #pragma unroll
  for (int k=1;k<17;k++) if (t >= offs[k]) s = k;
  int i = t - offs[s];
  float v = 0.f;
  if (i < szs[s]){
    if (*flag) v = ((const float*)pk.p[s])[i];
    else       v = b2f(((const bf16*)pk.p[s])[i]);
  }
  dst[t] = f2b(v);
}

// ---------------- setup kernels ----------------

// chunked local sort: each block sorts CHK edges by dst-bin into its OWN
// contiguous output region -> scattered stores stay L2-hot. (R6-proven shape.)
__global__ __launch_bounds__(512) void k_csort(const int* __restrict__ srcv,
      const int* __restrict__ dstv, const int* __restrict__ eav, int E_, int nb, int NC,
      unsigned int* __restrict__ bucketed, int* __restrict__ rs, int* __restrict__ bkt_cnt){
  __shared__ int lh[MAXBUCK];
  __shared__ int lofs[MAXBUCK];
  __shared__ int ws[9];
  int c = blockIdx.x, tid = threadIdx.x;
  int base = c*CHK, end = min(base+CHK, E_);
  for (int i=tid;i<nb;i+=512) lh[i]=0;
  __syncthreads();
  for (int i=base+tid; i<end; i+=512) atomicAdd(&lh[dstv[i]>>5], 1);
  __syncthreads();
  int lane=tid&63, w=tid>>6;
  int run=0;
  for (int bb=0; bb<nb; bb+=512){
    int i=bb+tid;
    int v=(i<nb)? lh[i]:0;
    int incl=v;
    #pragma unroll
    for (int off=1;off<64;off<<=1){
      int t=__shfl_up(incl,off,64);
      if (lane>=off) incl+=t;
    }
    if (lane==63) ws[w]=incl;
    __syncthreads();
    if (tid==0){ int r=0; for(int k=0;k<8;k++){int t=ws[k];ws[k]=r;r+=t;} ws[8]=r; }
    __syncthreads();
    if (i<nb) lofs[i]= run + ws[w] + incl - v;
    run += ws[8];
    __syncthreads();
  }
  for (int i=tid;i<nb;i+=512){
    rs[(size_t)i*NC + c] = base + lofs[i];
    int cntv = lh[i];
    if (cntv) atomicAdd(&bkt_cnt[i], cntv);
  }
  if (tid==0) rs[(size_t)nb*NC + c] = end;
  __syncthreads();
  for (int i=base+tid;i<end;i+=512){
    int d = dstv[i];
    int bin = d>>5;
    int pos = base + atomicAdd(&lofs[bin], 1);
    bucketed[pos] = (((unsigned)((d&31)*5 + eav[i]))<<17) | (unsigned)srcv[i];
  }
}

// per 32-node bin: compute own bkt prefix (scan kernel folded in), stage the
// bin's per-chunk runs into LDS (element-parallel binary-search placement),
// then 160-key counting sort (outputs: kptr, sorted_src, kperm).
// sorted_src stores src<<6 (premultiplied byte offset into the fp8 rows).
__global__ __launch_bounds__(256) void k_bsort2(const unsigned int* __restrict__ bucketed,
      const int* __restrict__ rs, int NC,
      const int* __restrict__ bkt_cnt, int nb, int E_,
      int* __restrict__ kptr, int* __restrict__ sorted_src,
      unsigned char* __restrict__ kperm){
  __shared__ unsigned sbuf[BCAP];
  __shared__ int rofs[MAXNC+1];
  __shared__ int rstart[MAXNC];
  __shared__ int scan2[2][MAXNC];
  __shared__ int cnt[160], sc[160], cur[160];
  __shared__ int red[256];
  __shared__ int sE[2];
  int b = blockIdx.x, tid = threadIdx.x;
  // --- prefix of bkt_cnt[0..b) (was k_scan) ---
  {
    int acc=0;
    for (int i=tid;i<b;i+=256) acc += bkt_cnt[i];
    red[tid]=acc; __syncthreads();
    #pragma unroll
    for (int off=128; off>0; off>>=1){
      if (tid<off) red[tid]+=red[tid+off];
      __syncthreads();
    }
    if (tid==0){ sE[0]=red[0]; sE[1]=red[0]+bkt_cnt[b]; }
    __syncthreads();
  }
  int s = sE[0], e = sE[1];
  int size = e - s;
  const int* rowA = rs + (size_t)b*NC;
  const int* rowB = rs + (size_t)(b+1)*NC;
  bool fits = (NC <= MAXNC);
  if (fits){
    for (int i=tid; i<MAXNC; i+=256){
      int v = 0;
      if (i < NC){
        int a = rowA[i];
        rstart[i] = a;
        v = rowB[i] - a;
      }
      scan2[0][i] = v;
    }
    __syncthreads();
    int pp = 0;
    #pragma unroll
    for (int off=1; off<MAXNC; off<<=1){
      for (int i=tid; i<MAXNC; i+=256){
        int nv = scan2[pp][i];
        if (i>=off) nv += scan2[pp][i-off];
        scan2[pp^1][i] = nv;
      }
      __syncthreads();
      pp ^= 1;
    }
    if (tid==0) rofs[0]=0;
    for (int i=tid; i<NC; i+=256) rofs[i+1] = scan2[pp][i];
    __syncthreads();
  }
  bool staged = fits && (size <= BCAP);
  if (staged){
    // element-parallel: find owning run via binary search, copy in
    for (int i=tid; i<size; i+=256){
      int lo=0, hi=NC-1;
      while (lo<hi){ int mid=(lo+hi+1)>>1; if (rofs[mid]<=i) lo=mid; else hi=mid-1; }
      sbuf[i] = bucketed[rstart[lo] + (i - rofs[lo])];
    }
  }
  __syncthreads();
  if (tid<160) cnt[tid]=0;
  __syncthreads();
  if (staged){
    for (int i=tid;i<size;i+=256) atomicAdd(&cnt[sbuf[i]>>17], 1);
  } else {
    for (int c2=0;c2<NC;c2++){
      int st=rowA[c2], ln=rowB[c2]-st;
      for (int k=tid;k<ln;k+=256) atomicAdd(&cnt[bucketed[st+k]>>17], 1);
    }
  }
  __syncthreads();
  if (tid<160) sc[tid]=cnt[tid];
  __syncthreads();
  #pragma unroll
  for (int off=1; off<160; off<<=1){
    int v = 0;
    if (tid<160 && tid>=off) v = sc[tid-off];
    __syncthreads();
    if (tid<160) sc[tid] += v;
    __syncthreads();
  }
  if (tid<160){
    int basek = s + sc[tid] - cnt[tid];
    kptr[b*160+tid] = basek;
    cur[tid] = basek;
  }
  if (b==nb-1 && tid==0) kptr[(size_t)nb*160] = e;
  if (tid<160){
    int hbase = (tid<80)? 0 : 80;
    int me = cnt[tid];
    int r = 0;
    for (int j=0;j<80;j++){
      int jj = hbase+j;
      int cj = cnt[jj];
      r += (cj>me) || (cj==me && jj<tid);
    }
    kperm[((size_t)b*2 + (tid<80?0:1))*80 + r] = (unsigned char)(tid - hbase);
  }
  __syncthreads();
  if (staged){
    for (int i=tid;i<size;i+=256){
      unsigned p = sbuf[i];
      int pos = atomicAdd(&cur[p>>17], 1);
      sorted_src[pos] = (int)((p & 0x1FFFFu)<<6);
    }
  } else {
    for (int c2=0;c2<NC;c2++){
      int st=rowA[c2], ln=rowB[c2]-st;
      for (int k=tid;k<ln;k+=256){
        unsigned p = bucketed[st+k];
        int pos = atomicAdd(&cur[p>>17], 1);
        sorted_src[pos] = (int)((p & 0x1FFFFu)<<6);
      }
    }
  }
}

__global__ __launch_bounds__(256) void k_lin0(const bf16* __restrict__ x,
      const bf16* __restrict__ w, const bf16* __restrict__ b,
      bf16* __restrict__ out0, bf16* __restrict__ h,
      unsigned char* __restrict__ hq, int N_){
  int idx = blockIdx.x*256+threadIdx.x;
  int n = idx>>6, o = idx&63;
  if (n>=N_) return;
  float acc = b2f(b[o]);
  #pragma unroll
  for (int k=0;k<15;k++) acc += b2f(x[n*15+k]) * b2f(w[k*64+o]);
  float hv = fmaxf(acc,0.f);
  bf16 v = f2b(hv);
  out0[idx]=v; h[idx]=v;
  float hvn = __shfl_xor(hv, 1);
  if (!(o&1)) *(unsigned short*)(hq + (size_t)n*64 + o) = f32pair_to_fp8(hv, hvn);
}

// generic row-major [K][NC] -> B-frag layout (zero-padded cols)
__device__ __forceinline__ void d_swz(const unsigned short* src, int KS, int NC,
                                      unsigned short* dst, int nfrag, int t){
  if (t >= nfrag*64) return;
  int lane=t&63, frag=t>>6, cb=frag/KS, ks=frag%KS;
  int c = cb*16 + (lane&15);
  #pragma unroll
  for (int j=0;j<8;j++){
    int k = ks*32 + ((lane>>4)<<3) + j;
    dst[t*8+j] = (c<NC)? src[k*NC+c] : (unsigned short)0;
  }
}

// fused prep
__global__ __launch_bounds__(256) void k_prep(const bf16* __restrict__ ee,
      const bf16* __restrict__ wih, const bf16* __restrict__ whh,
      const bf16* __restrict__ iw1, const bf16* __restrict__ jw1,
      const bf16* __restrict__ iw2, const bf16* __restrict__ jw2,
      unsigned short* __restrict__ wall, unsigned short* __restrict__ wgru,
      unsigned short* __restrict__ wr1, unsigned short* __restrict__ wiw2s,
      unsigned short* __restrict__ wjw2s,
      const int* __restrict__ batch, int N_, int G_, int* __restrict__ gptr){
  int blk = blockIdx.x, tid = threadIdx.x;
  if (blk < 10){
    int t = blk*256+tid;
    if (t<2560){
      int lane=t&63, frag=t>>6, ct=frag/10, ks=frag%10;
      int c = ct*16 + (lane&15);
      #pragma unroll
      for (int j=0;j<8;j++){
        int k = ks*32 + ((lane>>4)<<3) + j;
        int tt = k>>6, kc = k&63;
        wall[t*8+j] = ((const unsigned short*)ee)[tt*4096 + kc*64 + c];
      }
    }
  } else if (blk < 16){
    d_swz((const unsigned short*)wih, 2, 192, wgru, 24, (blk-10)*256+tid);
  } else if (blk < 22){
    d_swz((const unsigned short*)whh, 2, 192, wgru+12288, 24, (blk-16)*256+tid);
  } else if (blk < 26){
    d_swz((const unsigned short*)iw1, 4, 64, wr1, 16, (blk-22)*256+tid);
  } else if (blk < 28){
    d_swz((const unsigned short*)jw1, 2, 64, wr1+8192, 8, (blk-26)*256+tid);
  } else if (blk == 28){
    d_swz((const unsigned short*)iw2, 2, 12, wiw2s, 2, tid);
  } else if (blk == 29){
    d_swz((const unsigned short*)jw2, 2, 12, wjw2s, 2, tid);
  } else {
    int g = (blk-30)*256+tid;
    if (g <= G_){
      int lo=0, hi=N_;
      while (lo<hi){ int mid=(lo+hi)>>1; if (batch[mid] < g) lo=mid+1; else hi=mid; }
      gptr[g]=lo;
    }
  }
}

// ---------------- fused step: gather + NNConv + GRU ----------------
// Phase 1 gathers from the fp8 mirror hq (64 B/row). Phase 2/3 and the GRU
// state h stay bf16. Phase 3 writes both hout (bf16) and hqout (fp8).
// PARKED: 7 probes (R1/R3/R4/R5/R8/R10) show dur is insensitive to issue
// pattern AND bytes at fixed occupancy (line-request bound); only occupancy
// moves it. Do not touch.
__global__ __launch_bounds__(256,8) void k_step(const bf16* __restrict__ hin,
      bf16* __restrict__ hout,
      const unsigned char* __restrict__ hqin, unsigned char* __restrict__ hqout,
      const int* __restrict__ sorted_src, const int* __restrict__ kptr,
      const unsigned char* __restrict__ kperm,
      const unsigned short* __restrict__ wall, const unsigned short* __restrict__ wgru,
      const bf16* __restrict__ conv_bias, const bf16* __restrict__ bih,
      const bf16* __restrict__ bhh, int N_){
  __shared__ unsigned short Sb[80*SB];
  __shared__ int kp[81];
  __shared__ unsigned char pm[80];
  __shared__ char ubuf[SRCCAP*4 + 32];       // srcL (phase 0/1) | m_s (phase 2/3)
  int* srcL = (int*)ubuf;
  unsigned short* m_s = (unsigned short*)ubuf;
  int tid=threadIdx.x, lane=tid&63, w=tid>>6;
  int b=blockIdx.x;
  if (tid<81) kp[tid]=kptr[(size_t)b*80+tid];
  if (tid<80) pm[tid]=kperm[(size_t)b*80+tid];
  __syncthreads();
  int s0g = kp[0];
  int elen = kp[80]-s0g;
  int cap = (elen<=SRCCAP)? elen : 0;
  for (int i=tid;i<cap;i+=256) srcL[i]=sorted_src[s0g+i];   // already premultiplied <<6
  __syncthreads();
  int g=lane>>3, c=lane&7;
  const unsigned char* hp8 = hqin + (c<<3);
  const int sent = N_<<6;                    // byte offset of zeroed row N

  // ---- phase 1 (fp8 gather) ----
  auto run_phase1 = [&](auto GET){
    #pragma unroll 1
    for (int jo=0;jo<5;jo++){
      int pbase = jo*16 + w*4;
      int p  = pm[pbase + (g&3)];
      int p0 = pm[pbase];
      int st = kp[p]-s0g, len = kp[p+1]-kp[p];
      int maxLen = kp[p0+1]-kp[p0];
      int sub = g>>2;
      f32x2 a01={0.f,0.f}, a23={0.f,0.f}, a45={0.f,0.f}, a67={0.f,0.f};
      for (int base=0; base<maxLen; base+=8){
        uint2 hv[4];
        #pragma unroll
        for (int u=0;u<4;u++){
          int idx = base + sub*4 + u;
          int s = GET(st+idx);
          s = (idx < len)? s : sent;
          hv[u] = *(const uint2*)(hp8 + (size_t)s);
        }
        #pragma unroll
        for (int u=0;u<4;u++){
          a01 = pk_add(a01, cvt8lo(hv[u].x));
          a23 = pk_add(a23, cvt8hi(hv[u].x));
          a45 = pk_add(a45, cvt8lo(hv[u].y));
          a67 = pk_add(a67, cvt8hi(hv[u].y));
        }
      }
      float a[8] = {a01.x,a01.y,a23.x,a23.y,a45.x,a45.y,a67.x,a67.y};
      #pragma unroll
      for (int j=0;j<8;j++) a[j] += __shfl_xor(a[j], 32);
      if (g<4){
        uint4 v;
        v.x = cvtpk_bf16(a[0],a[1]);
        v.y = cvtpk_bf16(a[2],a[3]);
        v.z = cvtpk_bf16(a[4],a[5]);
        v.w = cvtpk_bf16(a[6],a[7]);
        *reinterpret_cast<uint4*>(&Sb[(size_t)p*SB + c*8]) = v;
      }
    }
  };
  if (cap) run_phase1([&](int rel){ return srcL[rel]; });
  else     run_phase1([&](int rel){ return sorted_src[s0g+rel]; });
  __syncthreads();

  // ---- phase 2: wave w -> coltile ct=w ----
  int q=lane>>4, mr=lane&15;
  {
    int ct = w;
    f32x4 acc={0.f,0.f,0.f,0.f};
    #pragma unroll
    for (int ks=0;ks<10;ks++){
      int k0 = ks*32 + q*8;
      int tt = k0>>6, ch = k0&63;
      short8 af = *reinterpret_cast<const short8*>(&Sb[(size_t)(mr*5+tt)*SB + ch]);
      short8 bfrag = *(const short8*)(wall + (size_t)((ct*10+ks)*64+lane)*8);
      acc = MFMA16(af, bfrag, acc);
    }
    int col = ct*16+mr;
    float bi = b2f(conv_bias[col]);
    #pragma unroll
    for (int r=0;r<4;r++){
      int nl = q*4+r;
      int deg = kp[nl*5+5]-kp[nl*5];
      float dv = 1.f/fmaxf((float)deg,1.f);
      m_s[nl*MSTR+col] = (unsigned short)f2bits(fmaxf(acc[r]*dv+bi,0.f));
    }
  }
  __syncthreads();

  // ---- phase 3: GRU, wave w -> coltile cc=w ----
  {
    int cc = w;
    int na = b*16+mr; if (na>N_-1) na=N_-1;
    short8 am0 = *(const short8*)(&m_s[mr*MSTR + q*8]);
    short8 am1 = *(const short8*)(&m_s[mr*MSTR + 32 + q*8]);
    short8 ah0 = ld_frag(hin + (size_t)na*64 + q*8);
    short8 ah1 = ld_frag(hin + (size_t)na*64 + 32 + q*8);
    const short8* Bw = reinterpret_cast<const short8*>(wgru);
    f32x4 xr={0.f,0.f,0.f,0.f}, xz=xr, xn=xr, hr=xr, hz=xr, hn=xr;
    xr = MFMA16(am0, Bw[((cc  )*2+0)*64+lane], xr);
    xr = MFMA16(am1, Bw[((cc  )*2+1)*64+lane], xr);
    xz = MFMA16(am0, Bw[((cc+4)*2+0)*64+lane], xz);
    xz = MFMA16(am1, Bw[((cc+4)*2+1)*64+lane], xz);
    xn = MFMA16(am0, Bw[((cc+8)*2+0)*64+lane], xn);
    xn = MFMA16(am1, Bw[((cc+8)*2+1)*64+lane], xn);
    hr = MFMA16(ah0, Bw[(24+(cc  )*2+0)*64+lane], hr);
    hr = MFMA16(ah1, Bw[(24+(cc  )*2+1)*64+lane], hr);
    hz = MFMA16(ah0, Bw[(24+(cc+4)*2+0)*64+lane], hz);
    hz = MFMA16(ah1, Bw[(24+(cc+4)*2+1)*64+lane], hz);
    hn = MFMA16(ah0, Bw[(24+(cc+8)*2+0)*64+lane], hn);
    hn = MFMA16(ah1, Bw[(24+(cc+8)*2+1)*64+lane], hn);
    int col = cc*16+mr;
    float bxr=b2f(bih[col]), bxz=b2f(bih[col+64]), bxn=b2f(bih[col+128]);
    float bhr=b2f(bhh[col]), bhz=b2f(bhh[col+64]), bhn=b2f(bhh[col+128]);
    #pragma unroll
    for (int r=0;r<4;r++){
      int row = q*4+r;
      int n = b*16+row;
      int nc = (n<N_)? n : N_-1;
      float rg = sigmf(xr[r]+bxr + hr[r]+bhr);
      float zg = sigmf(xz[r]+bxz + hz[r]+bhz);
      float ng = tanhfast(xn[r]+bxn + rg*(hn[r]+bhn));
      float ho = b2f(hin[(size_t)nc*64+col]);
      float hv = (1.f-zg)*ng + zg*ho;
      float hvn = __shfl_xor(hv, 1);
      if (n < N_){
        hout[(size_t)n*64+col] = f2b(hv);
        if (!(mr&1))
          *(unsigned short*)(hqout + (size_t)n*64 + col) = f32pair_to_fp8(hv, hvn);
      }
    }
  }
}

// ---------------- fused readout: read1 + read2 + graph accumulate ----------------
__global__ __launch_bounds__(256) void k_read(const bf16* __restrict__ h, const bf16* __restrict__ out0,
      const unsigned short* __restrict__ W, const bf16* __restrict__ ib1, const bf16* __restrict__ jb1,
      const unsigned short* __restrict__ iw2swz, const unsigned short* __restrict__ jw2swz,
      const bf16* __restrict__ ib2, const bf16* __restrict__ jb2,
      const int* __restrict__ batch, float* __restrict__ gatedG, int N_){
  __shared__ unsigned short lds[12288];      // iw1swz(8192) | jw1swz(4096)
  __shared__ unsigned short sbuf[64*72];
  __shared__ unsigned short tbuf[64*72];
  { const int* s=(const int*)W; int* d=(int*)lds;
    for (int i=threadIdx.x;i<6144;i+=256) d[i]=s[i]; }
  __syncthreads();
  int tid=threadIdx.x, lane=tid&63, w=tid>>6, q=lane>>4;
  int nb = blockIdx.x*64 + w*16;
  int ar = nb + (lane&15); if (ar>N_-1) ar=N_-1;
  short8 ah0 = ld_frag(h + (size_t)ar*64 + q*8),    ah1 = ld_frag(h + (size_t)ar*64 + 32 + q*8);
  short8 ao0 = ld_frag(out0 + (size_t)ar*64 + q*8), ao1 = ld_frag(out0 + (size_t)ar*64 + 32 + q*8);
  const short8* Bi = reinterpret_cast<const short8*>(lds);
  const short8* Bj = reinterpret_cast<const short8*>(lds + 8192);
  int colb = lane&15;
  for (int cb=0; cb<4; cb++){
    f32x4 ai = {0.f,0.f,0.f,0.f};
    ai = MFMA16(ah0, Bi[(cb*4+0)*64+lane], ai);
    ai = MFMA16(ah1, Bi[(cb*4+1)*64+lane], ai);
    ai = MFMA16(ao0, Bi[(cb*4+2)*64+lane], ai);
    ai = MFMA16(ao1, Bi[(cb*4+3)*64+lane], ai);
    f32x4 aj = {0.f,0.f,0.f,0.f};
    aj = MFMA16(ah0, Bj[(cb*2+0)*64+lane], aj);
    aj = MFMA16(ah1, Bj[(cb*2+1)*64+lane], aj);
    int col = cb*16 + colb;
    float bi=b2f(ib1[col]), bj=b2f(jb1[col]);
    #pragma unroll
    for (int r=0;r<4;r++){
      int lrow = w*16 + q*4 + r;
      sbuf[lrow*72+col] = (unsigned short)f2bits(sigmf(ai[r]+bi));
      tbuf[lrow*72+col] = (unsigned short)f2bits(sigmf(aj[r]+bj));
    }
  }
  __syncthreads();
  int mr = lane&15;
  short8 as0 = *(const short8*)(&sbuf[(w*16+mr)*72 + q*8]);
  short8 as1 = *(const short8*)(&sbuf[(w*16+mr)*72 + 32 + q*8]);
  short8 at0 = *(const short8*)(&tbuf[(w*16+mr)*72 + q*8]);
  short8 at1 = *(const short8*)(&tbuf[(w*16+mr)*72 + 32 + q*8]);
  const short8* Bi2 = reinterpret_cast<const short8*>(iw2swz);
  const short8* Bj2 = reinterpret_cast<const short8*>(jw2swz);
  f32x4 ai = {0.f,0.f,0.f,0.f};
  ai = MFMA16(as0, Bi2[lane], ai);
  ai = MFMA16(as1, Bi2[64+lane], ai);
  f32x4 aj = {0.f,0.f,0.f,0.f};
  aj = MFMA16(at0, Bj2[lane], aj);
  aj = MFMA16(at1, Bj2[64+lane], aj);
  int col = lane&15;
  if (col<12){
    float bi=b2f(ib2[col]), bj=b2f(jb2[col]);
    #pragma unroll
    for (int r=0;r<4;r++){
      int row = nb + q*4 + r;
      if (row < N_){
        float val = sigmf(ai[r]+bi)*(aj[r]+bj);
        atomicAdd(&gatedG[batch[row]*12+col], val);
      }
    }
  }
}

// final: convert G x 12 f32 accumulators to output dtype
__global__ __launch_bounds__(256) void k_fin(const float* __restrict__ gatedG,
      const int* __restrict__ flag, void* __restrict__ outp, int ng12){
  int f = *flag;
  for (int i=threadIdx.x; i<ng12; i+=256){
    float t = gatedG[i];
    if (f) ((float*)outp)[i] = t;
    else   ((bf16*) outp)[i] = f2b(t);
  }
}

// ---------------- launch ----------------

extern "C" void kernel_launch(void* const* d_in, const int* in_sizes, int n_in,
                              void* d_out, int out_size, void* d_ws, size_t ws_size,
                              hipStream_t stream){
  const int*  ei    = (const int*) d_in[1];
  const int*  ea    = (const int*) d_in[2];
  const int*  batch = (const int*) d_in[3];

  const int N_ = in_sizes[3];        // 100000
  const int E_ = in_sizes[2];        // 3200000
  const int G_ = out_size / 12;      // 256
  const int nb  = (N_ + 31) >> 5;    // 3125 bins of 32 nodes
  const int nbs = (N_ + 15) >> 4;    // 6250 buckets of 16 nodes (step kernel)
  const int NC  = (E_ + CHK - 1) / CHK;  // 391 sort chunks

  char* ws = (char*)d_ws;
  size_t off = 0;
  auto alloc = [&](size_t bytes)->size_t{
    size_t o = off; off += (bytes + 255) & ~(size_t)255; return o;
  };

  size_t oOut0   = alloc((size_t)N_*64*2);
  size_t oH0     = alloc((size_t)(N_+1)*64*2);   // +1 zeroed sentinel row
  size_t oH1     = alloc((size_t)(N_+1)*64*2);
  size_t oHq0    = alloc((size_t)(N_+1)*64);     // fp8 mirror of h0
  size_t oHq1    = alloc((size_t)(N_+1)*64);     // fp8 mirror of h1
  size_t oGatedG = alloc((size_t)G_*12*4);       // per-graph f32 accumulators
  size_t oBEdges = alloc((size_t)E_*4);
  size_t oSorted = alloc((size_t)E_*4 + 256);    // pad: phase-1 tail reads past end (masked)
  size_t oRS     = alloc((size_t)(nb+1)*NC*4);   // run starts, bin-major
  size_t oKptr   = alloc(((size_t)nb*160+2)*4);
  size_t oKperm  = alloc((size_t)nb*160);
  size_t oCanon  = alloc((size_t)CAN_TOT*2);
  size_t oCnt    = alloc((size_t)nb*4);
  size_t oGptr   = alloc((size_t)(G_+1)*4);
  size_t oFlag   = alloc(256);
  size_t oWall   = alloc((size_t)20480*2);
  size_t oWgru   = alloc((size_t)24576*2);
  size_t oWr1    = alloc((size_t)12288*2);
  size_t oWiw2   = alloc((size_t)1024*2);
  size_t oWjw2   = alloc((size_t)1024*2);

  bf16*  out0    = (bf16*)(ws + oOut0);
  bf16*  h0      = (bf16*)(ws + oH0);
  bf16*  h1      = (bf16*)(ws + oH1);
  unsigned char* hq0 = (unsigned char*)(ws + oHq0);
  unsigned char* hq1 = (unsigned char*)(ws + oHq1);
  float* gatedG  = (float*)(ws + oGatedG);
  unsigned int* bucketed = (unsigned int*)(ws + oBEdges);
  int*   sorted_src = (int*)(ws + oSorted);
  int*   rs      = (int*)(ws + oRS);
  int*   kptr    = (int*)(ws + oKptr);
  unsigned char* kperm = (unsigned char*)(ws + oKperm);
  bf16*  can     = (bf16*)(ws + oCanon);
  int*   bkt_cnt = (int*)(ws + oCnt);
  int*   gptr    = (int*)(ws + oGptr);
  int*   flag    = (int*)(ws + oFlag);
  unsigned short* wall  = (unsigned short*)(ws + oWall);
  unsigned short* wgru  = (unsigned short*)(ws + oWgru);
  unsigned short* wr1   = (unsigned short*)(ws + oWr1);
  unsigned short* wiw2s = (unsigned short*)(ws + oWiw2);
  unsigned short* wjw2s = (unsigned short*)(ws + oWjw2);

  const bf16* xC    = can + CAN_X;
  const bf16* l0wC  = can + CAN_L0W;
  const bf16* l0bC  = can + CAN_L0B;
  const bf16* eeC   = can + CAN_EE;
  const bf16* cbC   = can + CAN_CB;
  const bf16* wihC  = can + CAN_WIH;
  const bf16* whhC  = can + CAN_WHH;
  const bf16* bihC  = can + CAN_BIH;
  const bf16* bhhC  = can + CAN_BHH;
  const bf16* iw1C  = can + CAN_IW1;
  const bf16* ib1C  = can + CAN_IB1;
  const bf16* iw2C  = can + CAN_IW2;
  const bf16* ib2C  = can + CAN_IB2;
  const bf16* jw1C  = can + CAN_JW1;
  const bf16* jb1C  = can + CAN_JB1;
  const bf16* jw2C  = can + CAN_JW2;
  const bf16* jb2C  = can + CAN_JB2;

  PtrPack pk;
  pk.p[0]=d_in[0];  pk.p[1]=d_in[4];  pk.p[2]=d_in[5];  pk.p[3]=d_in[6];
  pk.p[4]=d_in[7];  pk.p[5]=d_in[8];  pk.p[6]=d_in[9];  pk.p[7]=d_in[10];
  pk.p[8]=d_in[11]; pk.p[9]=d_in[12]; pk.p[10]=d_in[13]; pk.p[11]=d_in[14];
  pk.p[12]=d_in[15]; pk.p[13]=d_in[16]; pk.p[14]=d_in[17]; pk.p[15]=d_in[18];
  pk.p[16]=d_in[19];

  const int gNw  = (N_+63)/64;       // 64 nodes / block (readout)

  // --- setup (sniff + workspace zeroing fused) ---
  k_sniff<<<3, 256, 0, stream>>>((const unsigned int*)d_in[0], flag,
                                 bkt_cnt, nb,
                                 (int*)(ws + oH0 + (size_t)N_*128),
                                 (int*)(ws + oH1 + (size_t)N_*128),
                                 (int*)(ws + oHq0 + (size_t)N_*64),
                                 (int*)(ws + oHq1 + (size_t)N_*64),
                                 gatedG, G_*12);
  k_canon<<<(CAN_TOT+255)/256, 256, 0, stream>>>(pk, flag, can);
  k_csort<<<NC, 512, 0, stream>>>(ei, ei + E_, ea, E_, nb, NC, bucketed, rs, bkt_cnt);
  k_bsort2<<<nb, 256, 0, stream>>>(bucketed, rs, NC, bkt_cnt, nb, E_, kptr, sorted_src, kperm);
  k_lin0<<<(N_*64+255)/256, 256, 0, stream>>>(xC, l0wC, l0bC, out0, h0, hq0, N_);
  k_prep<<<32, 256, 0, stream>>>(eeC, wihC, whhC, iw1C, jw1C, iw2C, jw2C,
                                 wall, wgru, wr1, wiw2s, wjw2s, batch, N_, G_, gptr);

  // --- 6 propagation steps (double-buffered h + fp8 mirror) ---
  bf16* hb[2] = {h0, h1};
  unsigned char* hqb[2] = {hq0, hq1};
  for (int step = 0; step < 6; ++step){
    k_step<<<nbs, 256, 0, stream>>>(hb[step&1], hb[(step+1)&1],
                                    hqb[step&1], hqb[(step+1)&1],
                                    sorted_src, kptr, kperm,
                                    wall, wgru, cbC, bihC, bhhC, N_);
  }
  bf16* hfin = hb[0];   // after 6 steps

  // --- readout (graph-sum fused via atomics) + final convert ---
  k_read<<<gNw, 256, 0, stream>>>(hfin, out0, wr1, ib1C, jb1C, wiw2s, wjw2s,
                                  ib2C, jb2C, batch, gatedG, N_);
  k_fin<<<1, 256, 0, stream>>>(gatedG, flag, d_out, G_*12);
}

// Round 13
// 652.775 us; speedup vs baseline: 1.1417x; 1.1417x over previous
//
#include <hip/hip_runtime.h>
#include <hip/hip_bf16.h>

typedef __hip_bfloat16 bf16;
using short8 = __attribute__((ext_vector_type(8))) short;
using f32x4  = __attribute__((ext_vector_type(4))) float;
using f32x2  = __attribute__((ext_vector_type(2))) float;

#define MFMA16(a,b,c) __builtin_amdgcn_mfma_f32_16x16x32_bf16((a),(b),(c),0,0,0)
#define MAXBUCK 4096   // dst>>5 bins: supports N <= 131072
#define SB 72          // LDS stride (bf16 shorts) for S rows (144B, 16B-aligned)
#define MSTR 72        // LDS stride (bf16) for m rows
#define SRCCAP 1024    // staged src indices per bucket (mean 512, 22 sigma headroom)
#define CHK 8192       // edges per sort chunk (391 chunks -> csort fills the GPU; R6-proven)
#define MAXNC 512      // bsort2 parallel-scan capacity (NC = ceil(E/CHK) = 391)
#define BCAP 2816      // bsort2 staging cap (bin mean 1024, sd 32 -> 56 sigma)

__device__ __forceinline__ float b2f(bf16 v){ return __bfloat162float(v); }
__device__ __forceinline__ bf16  f2b(float v){ return __float2bfloat16(v); }
__device__ __forceinline__ float sigmf(float x){ return 1.f/(1.f+__expf(-x)); }
__device__ __forceinline__ float tanhfast(float x){
  x = fminf(fmaxf(x,-15.f),15.f);
  float e = __expf(2.f*x);
  return (e-1.f)/(e+1.f);
}
__device__ __forceinline__ short8 ld_frag(const bf16* p){
  return *reinterpret_cast<const short8*>(p);
}
__device__ __forceinline__ short f2bits(float f){
  unsigned u = __builtin_bit_cast(unsigned, f);
  unsigned r = (u + 0x7FFFu + ((u>>16)&1u)) >> 16;
  return (short)r;
}
__device__ __forceinline__ f32x2 pk_add(f32x2 a, f32x2 b){
  f32x2 d;
  asm("v_pk_add_f32 %0, %1, %2" : "=v"(d) : "v"(a), "v"(b));
  return d;
}
__device__ __forceinline__ unsigned cvtpk_bf16(float lo, float hi){
  unsigned r;
  asm("v_cvt_pk_bf16_f32 %0, %1, %2" : "=v"(r) : "v"(lo), "v"(hi));
  return r;
}

// ---------------- fp8 e4m3 helpers (pure inline asm, gfx950) ----
__device__ __forceinline__ f32x2 cvt8lo(unsigned w){
  f32x2 r;
  asm("v_cvt_pk_f32_fp8 %0, %1" : "=v"(r) : "v"(w));
  return r;
}
__device__ __forceinline__ f32x2 cvt8hi(unsigned w){
  return cvt8lo(w >> 16);
}
__device__ __forceinline__ unsigned short f32pair_to_fp8(float a, float b){
  unsigned r = 0;
  asm("v_cvt_pk_fp8_f32 %0, %1, %2" : "+v"(r) : "v"(a), "v"(b));
  return (unsigned short)(r & 0xffffu);
}

// ---------------- dtype sniff + workspace zeroing ----------------
// block 0: sniff dtype of x; block 1: zero bkt_cnt; block 2: zero sentinels.
__global__ void k_sniff(const unsigned int* __restrict__ x, int* __restrict__ flag,
      int* __restrict__ bkt_cnt, int nb,
      int* __restrict__ s0, int* __restrict__ s1,
      int* __restrict__ s2, int* __restrict__ s3){
  int t = threadIdx.x;
  if (blockIdx.x == 1){
    for (int i=t;i<nb;i+=256) bkt_cnt[i]=0;
    return;
  }
  if (blockIdx.x == 2){
    if (t<32){ s0[t]=0; s1[t]=0; }
    if (t<16){ s2[t]=0; s3[t]=0; }
    return;
  }
  int good = 0;
  for (int i=t; i<4096; i+=256){
    unsigned w = x[i];
    unsigned e = (w>>23)&0xFFu;
    unsigned m = w & 0x7FFFFFFFu;
    if ((e>=100u && e<=150u) || m==0u) good++;
  }
  __shared__ int sm[256];
  sm[t]=good; __syncthreads();
  if (t==0){ int s=0; for (int k=0;k<256;k++) s+=sm[k]; *flag = (s>2048)?1:0; }
}

struct PtrPack { const void* p[17]; };

#define CAN_X     0
#define CAN_L0W   1500032
#define CAN_L0B   1500992
#define CAN_EE    1501056
#define CAN_CB    1521536
#define CAN_WIH   1521600
#define CAN_WHH   1533888
#define CAN_BIH   1546176
#define CAN_BHH   1546368
#define CAN_IW1   1546560
#define CAN_IB1   1554752
#define CAN_IW2   1554816
#define CAN_IB2   1555584
#define CAN_JW1   1555648
#define CAN_JB1   1559744
#define CAN_JW2   1559808
#define CAN_JB2   1560576
#define CAN_TOT   1560640

__global__ void k_canon(PtrPack pk, const int* __restrict__ flag, bf16* __restrict__ dst){
  static const int offs[17] = {CAN_X,CAN_L0W,CAN_L0B,CAN_EE,CAN_CB,CAN_WIH,CAN_WHH,
    CAN_BIH,CAN_BHH,CAN_IW1,CAN_IB1,CAN_IW2,CAN_IB2,CAN_JW1,CAN_JB1,CAN_JW2,CAN_JB2};
  static const int szs[17]  = {1500000,960,64,20480,64,12288,12288,192,192,8192,64,768,12,4096,64,768,12};
  int t = blockIdx.x*256+threadIdx.x;
  if (t >= CAN_TOT) return;
  int s = 0;
  #pragma unroll
  for (int k=1;k<17;k++) if (t >= offs[k]) s = k;
  int i = t - offs[s];
  float v = 0.f;
  if (i < szs[s]){
    if (*flag) v = ((const float*)pk.p[s])[i];
    else       v = b2f(((const bf16*)pk.p[s])[i]);
  }
  dst[t] = f2b(v);
}

// ---------------- setup kernels ----------------

// chunked local sort: each block sorts CHK edges by dst-bin into its OWN
// contiguous output region -> scattered stores stay L2-hot. (R6-proven shape.)
__global__ __launch_bounds__(512) void k_csort(const int* __restrict__ srcv,
      const int* __restrict__ dstv, const int* __restrict__ eav, int E_, int nb, int NC,
      unsigned int* __restrict__ bucketed, int* __restrict__ rs, int* __restrict__ bkt_cnt){
  __shared__ int lh[MAXBUCK];
  __shared__ int lofs[MAXBUCK];
  __shared__ int ws[9];
  int c = blockIdx.x, tid = threadIdx.x;
  int base = c*CHK, end = min(base+CHK, E_);
  for (int i=tid;i<nb;i+=512) lh[i]=0;
  __syncthreads();
  for (int i=base+tid; i<end; i+=512) atomicAdd(&lh[dstv[i]>>5], 1);
  __syncthreads();
  int lane=tid&63, w=tid>>6;
  int run=0;
  for (int bb=0; bb<nb; bb+=512){
    int i=bb+tid;
    int v=(i<nb)? lh[i]:0;
    int incl=v;
    #pragma unroll
    for (int off=1;off<64;off<<=1){
      int t=__shfl_up(incl,off,64);
      if (lane>=off) incl+=t;
    }
    if (lane==63) ws[w]=incl;
    __syncthreads();
    if (tid==0){ int r=0; for(int k=0;k<8;k++){int t=ws[k];ws[k]=r;r+=t;} ws[8]=r; }
    __syncthreads();
    if (i<nb) lofs[i]= run + ws[w] + incl - v;
    run += ws[8];
    __syncthreads();
  }
  for (int i=tid;i<nb;i+=512){
    rs[(size_t)i*NC + c] = base + lofs[i];
    int cntv = lh[i];
    if (cntv) atomicAdd(&bkt_cnt[i], cntv);
  }
  if (tid==0) rs[(size_t)nb*NC + c] = end;
  __syncthreads();
  for (int i=base+tid;i<end;i+=512){
    int d = dstv[i];
    int bin = d>>5;
    int pos = base + atomicAdd(&lofs[bin], 1);
    bucketed[pos] = (((unsigned)((d&31)*5 + eav[i]))<<17) | (unsigned)srcv[i];
  }
}

// per 32-node bin: compute own bkt prefix (scan kernel folded in), stage the
// bin's per-chunk runs into LDS (element-parallel binary-search placement),
// then 160-key counting sort (outputs: kptr, sorted_src, kperm).
// sorted_src stores src<<6 (premultiplied byte offset into the fp8 rows).
__global__ __launch_bounds__(256) void k_bsort2(const unsigned int* __restrict__ bucketed,
      const int* __restrict__ rs, int NC,
      const int* __restrict__ bkt_cnt, int nb, int E_,
      int* __restrict__ kptr, int* __restrict__ sorted_src,
      unsigned char* __restrict__ kperm){
  __shared__ unsigned sbuf[BCAP];
  __shared__ int rofs[MAXNC+1];
  __shared__ int rstart[MAXNC];
  __shared__ int scan2[2][MAXNC];
  __shared__ int cnt[160], sc[160], cur[160];
  __shared__ int red[256];
  __shared__ int sE[2];
  int b = blockIdx.x, tid = threadIdx.x;
  // --- prefix of bkt_cnt[0..b) (was k_scan) ---
  {
    int acc=0;
    for (int i=tid;i<b;i+=256) acc += bkt_cnt[i];
    red[tid]=acc; __syncthreads();
    #pragma unroll
    for (int off=128; off>0; off>>=1){
      if (tid<off) red[tid]+=red[tid+off];
      __syncthreads();
    }
    if (tid==0){ sE[0]=red[0]; sE[1]=red[0]+bkt_cnt[b]; }
    __syncthreads();
  }
  int s = sE[0], e = sE[1];
  int size = e - s;
  const int* rowA = rs + (size_t)b*NC;
  const int* rowB = rs + (size_t)(b+1)*NC;
  bool fits = (NC <= MAXNC);
  if (fits){
    for (int i=tid; i<MAXNC; i+=256){
      int v = 0;
      if (i < NC){
        int a = rowA[i];
        rstart[i] = a;
        v = rowB[i] - a;
      }
      scan2[0][i] = v;
    }
    __syncthreads();
    int pp = 0;
    #pragma unroll
    for (int off=1; off<MAXNC; off<<=1){
      for (int i=tid; i<MAXNC; i+=256){
        int nv = scan2[pp][i];
        if (i>=off) nv += scan2[pp][i-off];
        scan2[pp^1][i] = nv;
      }
      __syncthreads();
      pp ^= 1;
    }
    if (tid==0) rofs[0]=0;
    for (int i=tid; i<NC; i+=256) rofs[i+1] = scan2[pp][i];
    __syncthreads();
  }
  bool staged = fits && (size <= BCAP);
  if (staged){
    // element-parallel: find owning run via binary search, copy in
    for (int i=tid; i<size; i+=256){
      int lo=0, hi=NC-1;
      while (lo<hi){ int mid=(lo+hi+1)>>1; if (rofs[mid]<=i) lo=mid; else hi=mid-1; }
      sbuf[i] = bucketed[rstart[lo] + (i - rofs[lo])];
    }
  }
  __syncthreads();
  if (tid<160) cnt[tid]=0;
  __syncthreads();
  if (staged){
    for (int i=tid;i<size;i+=256) atomicAdd(&cnt[sbuf[i]>>17], 1);
  } else {
    for (int c2=0;c2<NC;c2++){
      int st=rowA[c2], ln=rowB[c2]-st;
      for (int k=tid;k<ln;k+=256) atomicAdd(&cnt[bucketed[st+k]>>17], 1);
    }
  }
  __syncthreads();
  if (tid<160) sc[tid]=cnt[tid];
  __syncthreads();
  #pragma unroll
  for (int off=1; off<160; off<<=1){
    int v = 0;
    if (tid<160 && tid>=off) v = sc[tid-off];
    __syncthreads();
    if (tid<160) sc[tid] += v;
    __syncthreads();
  }
  if (tid<160){
    int basek = s + sc[tid] - cnt[tid];
    kptr[b*160+tid] = basek;
    cur[tid] = basek;
  }
  if (b==nb-1 && tid==0) kptr[(size_t)nb*160] = e;
  if (tid<160){
    int hbase = (tid<80)? 0 : 80;
    int me = cnt[tid];
    int r = 0;
    for (int j=0;j<80;j++){
      int jj = hbase+j;
      int cj = cnt[jj];
      r += (cj>me) || (cj==me && jj<tid);
    }
    kperm[((size_t)b*2 + (tid<80?0:1))*80 + r] = (unsigned char)(tid - hbase);
  }
  __syncthreads();
  if (staged){
    for (int i=tid;i<size;i+=256){
      unsigned p = sbuf[i];
      int pos = atomicAdd(&cur[p>>17], 1);
      sorted_src[pos] = (int)((p & 0x1FFFFu)<<6);
    }
  } else {
    for (int c2=0;c2<NC;c2++){
      int st=rowA[c2], ln=rowB[c2]-st;
      for (int k=tid;k<ln;k+=256){
        unsigned p = bucketed[st+k];
        int pos = atomicAdd(&cur[p>>17], 1);
        sorted_src[pos] = (int)((p & 0x1FFFFu)<<6);
      }
    }
  }
}

__global__ __launch_bounds__(256) void k_lin0(const bf16* __restrict__ x,
      const bf16* __restrict__ w, const bf16* __restrict__ b,
      bf16* __restrict__ out0, bf16* __restrict__ h,
      unsigned char* __restrict__ hq, int N_){
  int idx = blockIdx.x*256+threadIdx.x;
  int n = idx>>6, o = idx&63;
  if (n>=N_) return;
  float acc = b2f(b[o]);
  #pragma unroll
  for (int k=0;k<15;k++) acc += b2f(x[n*15+k]) * b2f(w[k*64+o]);
  float hv = fmaxf(acc,0.f);
  bf16 v = f2b(hv);
  out0[idx]=v; h[idx]=v;
  float hvn = __shfl_xor(hv, 1);
  if (!(o&1)) *(unsigned short*)(hq + (size_t)n*64 + o) = f32pair_to_fp8(hv, hvn);
}

// generic row-major [K][NC] -> B-frag layout (zero-padded cols)
__device__ __forceinline__ void d_swz(const unsigned short* src, int KS, int NC,
                                      unsigned short* dst, int nfrag, int t){
  if (t >= nfrag*64) return;
  int lane=t&63, frag=t>>6, cb=frag/KS, ks=frag%KS;
  int c = cb*16 + (lane&15);
  #pragma unroll
  for (int j=0;j<8;j++){
    int k = ks*32 + ((lane>>4)<<3) + j;
    dst[t*8+j] = (c<NC)? src[k*NC+c] : (unsigned short)0;
  }
}

// fused prep
__global__ __launch_bounds__(256) void k_prep(const bf16* __restrict__ ee,
      const bf16* __restrict__ wih, const bf16* __restrict__ whh,
      const bf16* __restrict__ iw1, const bf16* __restrict__ jw1,
      const bf16* __restrict__ iw2, const bf16* __restrict__ jw2,
      unsigned short* __restrict__ wall, unsigned short* __restrict__ wgru,
      unsigned short* __restrict__ wr1, unsigned short* __restrict__ wiw2s,
      unsigned short* __restrict__ wjw2s,
      const int* __restrict__ batch, int N_, int G_, int* __restrict__ gptr){
  int blk = blockIdx.x, tid = threadIdx.x;
  if (blk < 10){
    int t = blk*256+tid;
    if (t<2560){
      int lane=t&63, frag=t>>6, ct=frag/10, ks=frag%10;
      int c = ct*16 + (lane&15);
      #pragma unroll
      for (int j=0;j<8;j++){
        int k = ks*32 + ((lane>>4)<<3) + j;
        int tt = k>>6, kc = k&63;
        wall[t*8+j] = ((const unsigned short*)ee)[tt*4096 + kc*64 + c];
      }
    }
  } else if (blk < 16){
    d_swz((const unsigned short*)wih, 2, 192, wgru, 24, (blk-10)*256+tid);
  } else if (blk < 22){
    d_swz((const unsigned short*)whh, 2, 192, wgru+12288, 24, (blk-16)*256+tid);
  } else if (blk < 26){
    d_swz((const unsigned short*)iw1, 4, 64, wr1, 16, (blk-22)*256+tid);
  } else if (blk < 28){
    d_swz((const unsigned short*)jw1, 2, 64, wr1+8192, 8, (blk-26)*256+tid);
  } else if (blk == 28){
    d_swz((const unsigned short*)iw2, 2, 12, wiw2s, 2, tid);
  } else if (blk == 29){
    d_swz((const unsigned short*)jw2, 2, 12, wjw2s, 2, tid);
  } else {
    int g = (blk-30)*256+tid;
    if (g <= G_){
      int lo=0, hi=N_;
      while (lo<hi){ int mid=(lo+hi)>>1; if (batch[mid] < g) lo=mid+1; else hi=mid; }
      gptr[g]=lo;
    }
  }
}

// ---------------- fused step: gather + NNConv + GRU ----------------
// Phase 1 gathers from the fp8 mirror hq (64 B/row). Phase 2/3 and the GRU
// state h stay bf16. Phase 3 writes both hout (bf16) and hqout (fp8).
// PARKED: 7 probes (R1/R3/R4/R5/R8/R10) show dur is insensitive to issue
// pattern AND bytes at fixed occupancy (line-request bound); only occupancy
// moves it. Do not touch.
__global__ __launch_bounds__(256,8) void k_step(const bf16* __restrict__ hin,
      bf16* __restrict__ hout,
      const unsigned char* __restrict__ hqin, unsigned char* __restrict__ hqout,
      const int* __restrict__ sorted_src, const int* __restrict__ kptr,
      const unsigned char* __restrict__ kperm,
      const unsigned short* __restrict__ wall, const unsigned short* __restrict__ wgru,
      const bf16* __restrict__ conv_bias, const bf16* __restrict__ bih,
      const bf16* __restrict__ bhh, int N_){
  __shared__ unsigned short Sb[80*SB];
  __shared__ int kp[81];
  __shared__ unsigned char pm[80];
  __shared__ char ubuf[SRCCAP*4 + 32];       // srcL (phase 0/1) | m_s (phase 2/3)
  int* srcL = (int*)ubuf;
  unsigned short* m_s = (unsigned short*)ubuf;
  int tid=threadIdx.x, lane=tid&63, w=tid>>6;
  int b=blockIdx.x;
  if (tid<81) kp[tid]=kptr[(size_t)b*80+tid];
  if (tid<80) pm[tid]=kperm[(size_t)b*80+tid];
  __syncthreads();
  int s0g = kp[0];
  int elen = kp[80]-s0g;
  int cap = (elen<=SRCCAP)? elen : 0;
  for (int i=tid;i<cap;i+=256) srcL[i]=sorted_src[s0g+i];   // already premultiplied <<6
  __syncthreads();
  int g=lane>>3, c=lane&7;
  const unsigned char* hp8 = hqin + (c<<3);
  const int sent = N_<<6;                    // byte offset of zeroed row N

  // ---- phase 1 (fp8 gather) ----
  auto run_phase1 = [&](auto GET){
    #pragma unroll 1
    for (int jo=0;jo<5;jo++){
      int pbase = jo*16 + w*4;
      int p  = pm[pbase + (g&3)];
      int p0 = pm[pbase];
      int st = kp[p]-s0g, len = kp[p+1]-kp[p];
      int maxLen = kp[p0+1]-kp[p0];
      int sub = g>>2;
      f32x2 a01={0.f,0.f}, a23={0.f,0.f}, a45={0.f,0.f}, a67={0.f,0.f};
      for (int base=0; base<maxLen; base+=8){
        uint2 hv[4];
        #pragma unroll
        for (int u=0;u<4;u++){
          int idx = base + sub*4 + u;
          int s = GET(st+idx);
          s = (idx < len)? s : sent;
          hv[u] = *(const uint2*)(hp8 + (size_t)s);
        }
        #pragma unroll
        for (int u=0;u<4;u++){
          a01 = pk_add(a01, cvt8lo(hv[u].x));
          a23 = pk_add(a23, cvt8hi(hv[u].x));
          a45 = pk_add(a45, cvt8lo(hv[u].y));
          a67 = pk_add(a67, cvt8hi(hv[u].y));
        }
      }
      float a[8] = {a01.x,a01.y,a23.x,a23.y,a45.x,a45.y,a67.x,a67.y};
      #pragma unroll
      for (int j=0;j<8;j++) a[j] += __shfl_xor(a[j], 32);
      if (g<4){
        uint4 v;
        v.x = cvtpk_bf16(a[0],a[1]);
        v.y = cvtpk_bf16(a[2],a[3]);
        v.z = cvtpk_bf16(a[4],a[5]);
        v.w = cvtpk_bf16(a[6],a[7]);
        *reinterpret_cast<uint4*>(&Sb[(size_t)p*SB + c*8]) = v;
      }
    }
  };
  if (cap) run_phase1([&](int rel){ return srcL[rel]; });
  else     run_phase1([&](int rel){ return sorted_src[s0g+rel]; });
  __syncthreads();

  // ---- phase 2: wave w -> coltile ct=w ----
  int q=lane>>4, mr=lane&15;
  {
    int ct = w;
    f32x4 acc={0.f,0.f,0.f,0.f};
    #pragma unroll
    for (int ks=0;ks<10;ks++){
      int k0 = ks*32 + q*8;
      int tt = k0>>6, ch = k0&63;
      short8 af = *reinterpret_cast<const short8*>(&Sb[(size_t)(mr*5+tt)*SB + ch]);
      short8 bfrag = *(const short8*)(wall + (size_t)((ct*10+ks)*64+lane)*8);
      acc = MFMA16(af, bfrag, acc);
    }
    int col = ct*16+mr;
    float bi = b2f(conv_bias[col]);
    #pragma unroll
    for (int r=0;r<4;r++){
      int nl = q*4+r;
      int deg = kp[nl*5+5]-kp[nl*5];
      float dv = 1.f/fmaxf((float)deg,1.f);
      m_s[nl*MSTR+col] = (unsigned short)f2bits(fmaxf(acc[r]*dv+bi,0.f));
    }
  }
  __syncthreads();

  // ---- phase 3: GRU, wave w -> coltile cc=w ----
  {
    int cc = w;
    int na = b*16+mr; if (na>N_-1) na=N_-1;
    short8 am0 = *(const short8*)(&m_s[mr*MSTR + q*8]);
    short8 am1 = *(const short8*)(&m_s[mr*MSTR + 32 + q*8]);
    short8 ah0 = ld_frag(hin + (size_t)na*64 + q*8);
    short8 ah1 = ld_frag(hin + (size_t)na*64 + 32 + q*8);
    const short8* Bw = reinterpret_cast<const short8*>(wgru);
    f32x4 xr={0.f,0.f,0.f,0.f}, xz=xr, xn=xr, hr=xr, hz=xr, hn=xr;
    xr = MFMA16(am0, Bw[((cc  )*2+0)*64+lane], xr);
    xr = MFMA16(am1, Bw[((cc  )*2+1)*64+lane], xr);
    xz = MFMA16(am0, Bw[((cc+4)*2+0)*64+lane], xz);
    xz = MFMA16(am1, Bw[((cc+4)*2+1)*64+lane], xz);
    xn = MFMA16(am0, Bw[((cc+8)*2+0)*64+lane], xn);
    xn = MFMA16(am1, Bw[((cc+8)*2+1)*64+lane], xn);
    hr = MFMA16(ah0, Bw[(24+(cc  )*2+0)*64+lane], hr);
    hr = MFMA16(ah1, Bw[(24+(cc  )*2+1)*64+lane], hr);
    hz = MFMA16(ah0, Bw[(24+(cc+4)*2+0)*64+lane], hz);
    hz = MFMA16(ah1, Bw[(24+(cc+4)*2+1)*64+lane], hz);
    hn = MFMA16(ah0, Bw[(24+(cc+8)*2+0)*64+lane], hn);
    hn = MFMA16(ah1, Bw[(24+(cc+8)*2+1)*64+lane], hn);
    int col = cc*16+mr;
    float bxr=b2f(bih[col]), bxz=b2f(bih[col+64]), bxn=b2f(bih[col+128]);
    float bhr=b2f(bhh[col]), bhz=b2f(bhh[col+64]), bhn=b2f(bhh[col+128]);
    #pragma unroll
    for (int r=0;r<4;r++){
      int row = q*4+r;
      int n = b*16+row;
      int nc = (n<N_)? n : N_-1;
      float rg = sigmf(xr[r]+bxr + hr[r]+bhr);
      float zg = sigmf(xz[r]+bxz + hz[r]+bhz);
      float ng = tanhfast(xn[r]+bxn + rg*(hn[r]+bhn));
      float ho = b2f(hin[(size_t)nc*64+col]);
      float hv = (1.f-zg)*ng + zg*ho;
      float hvn = __shfl_xor(hv, 1);
      if (n < N_){
        hout[(size_t)n*64+col] = f2b(hv);
        if (!(mr&1))
          *(unsigned short*)(hqout + (size_t)n*64 + col) = f32pair_to_fp8(hv, hvn);
      }
    }
  }
}

// ---------------- fused readout: (read1 + read2) ----------------
__global__ __launch_bounds__(256) void k_read(const bf16* __restrict__ h, const bf16* __restrict__ out0,
      const unsigned short* __restrict__ W, const bf16* __restrict__ ib1, const bf16* __restrict__ jb1,
      const unsigned short* __restrict__ iw2swz, const unsigned short* __restrict__ jw2swz,
      const bf16* __restrict__ ib2, const bf16* __restrict__ jb2,
      float* __restrict__ gated, int N_){
  __shared__ unsigned short lds[12288];      // iw1swz(8192) | jw1swz(4096)
  __shared__ unsigned short sbuf[64*72];
  __shared__ unsigned short tbuf[64*72];
  { const int* s=(const int*)W; int* d=(int*)lds;
    for (int i=threadIdx.x;i<6144;i+=256) d[i]=s[i]; }
  __syncthreads();
  int tid=threadIdx.x, lane=tid&63, w=tid>>6, q=lane>>4;
  int nb = blockIdx.x*64 + w*16;
  int ar = nb + (lane&15); if (ar>N_-1) ar=N_-1;
  short8 ah0 = ld_frag(h + (size_t)ar*64 + q*8),    ah1 = ld_frag(h + (size_t)ar*64 + 32 + q*8);
  short8 ao0 = ld_frag(out0 + (size_t)ar*64 + q*8), ao1 = ld_frag(out0 + (size_t)ar*64 + 32 + q*8);
  const short8* Bi = reinterpret_cast<const short8*>(lds);
  const short8* Bj = reinterpret_cast<const short8*>(lds + 8192);
  int colb = lane&15;
  for (int cb=0; cb<4; cb++){
    f32x4 ai = {0.f,0.f,0.f,0.f};
    ai = MFMA16(ah0, Bi[(cb*4+0)*64+lane], ai);
    ai = MFMA16(ah1, Bi[(cb*4+1)*64+lane], ai);
    ai = MFMA16(ao0, Bi[(cb*4+2)*64+lane], ai);
    ai = MFMA16(ao1, Bi[(cb*4+3)*64+lane], ai);
    f32x4 aj = {0.f,0.f,0.f,0.f};
    aj = MFMA16(ah0, Bj[(cb*2+0)*64+lane], aj);
    aj = MFMA16(ah1, Bj[(cb*2+1)*64+lane], aj);
    int col = cb*16 + colb;
    float bi=b2f(ib1[col]), bj=b2f(jb1[col]);
    #pragma unroll
    for (int r=0;r<4;r++){
      int lrow = w*16 + q*4 + r;
      sbuf[lrow*72+col] = (unsigned short)f2bits(sigmf(ai[r]+bi));
      tbuf[lrow*72+col] = (unsigned short)f2bits(sigmf(aj[r]+bj));
    }
  }
  __syncthreads();
  int mr = lane&15;
  short8 as0 = *(const short8*)(&sbuf[(w*16+mr)*72 + q*8]);
  short8 as1 = *(const short8*)(&sbuf[(w*16+mr)*72 + 32 + q*8]);
  short8 at0 = *(const short8*)(&tbuf[(w*16+mr)*72 + q*8]);
  short8 at1 = *(const short8*)(&tbuf[(w*16+mr)*72 + 32 + q*8]);
  const short8* Bi2 = reinterpret_cast<const short8*>(iw2swz);
  const short8* Bj2 = reinterpret_cast<const short8*>(jw2swz);
  f32x4 ai = {0.f,0.f,0.f,0.f};
  ai = MFMA16(as0, Bi2[lane], ai);
  ai = MFMA16(as1, Bi2[64+lane], ai);
  f32x4 aj = {0.f,0.f,0.f,0.f};
  aj = MFMA16(at0, Bj2[lane], aj);
  aj = MFMA16(at1, Bj2[64+lane], aj);
  int col = lane&15;
  if (col<12){
    float bi=b2f(ib2[col]), bj=b2f(jb2[col]);
    #pragma unroll
    for (int r=0;r<4;r++){
      int row = nb + q*4 + r;
      if (row < N_) gated[(size_t)row*12+col] = sigmf(ai[r]+bi)*(aj[r]+bj);
    }
  }
}

__global__ __launch_bounds__(256) void k_graphsum(const float* __restrict__ gated,
      const int* __restrict__ gptr, const int* __restrict__ flag, void* __restrict__ outp){
  int g = blockIdx.x;
  int s = gptr[g], e = gptr[g+1];
  int tid = threadIdx.x;
  int c = tid & 15, rg = tid >> 4;
  float acc = 0.f;
  if (c < 12)
    for (int row = s + rg; row < e; row += 16) acc += gated[(size_t)row*12 + c];
  __shared__ float sm[256];
  sm[tid] = acc;
  __syncthreads();
  if (rg == 0 && c < 12){
    float t = 0.f;
    for (int k=0;k<16;k++) t += sm[k*16 + c];
    if (*flag) ((float*)outp)[g*12 + c] = t;
    else       ((bf16*) outp)[g*12 + c] = f2b(t);
  }
}

// ---------------- launch ----------------

extern "C" void kernel_launch(void* const* d_in, const int* in_sizes, int n_in,
                              void* d_out, int out_size, void* d_ws, size_t ws_size,
                              hipStream_t stream){
  const int*  ei    = (const int*) d_in[1];
  const int*  ea    = (const int*) d_in[2];
  const int*  batch = (const int*) d_in[3];

  const int N_ = in_sizes[3];        // 100000
  const int E_ = in_sizes[2];        // 3200000
  const int G_ = out_size / 12;      // 256
  const int nb  = (N_ + 31) >> 5;    // 3125 bins of 32 nodes
  const int nbs = (N_ + 15) >> 4;    // 6250 buckets of 16 nodes (step kernel)
  const int NC  = (E_ + CHK - 1) / CHK;  // 391 sort chunks

  char* ws = (char*)d_ws;
  size_t off = 0;
  auto alloc = [&](size_t bytes)->size_t{
    size_t o = off; off += (bytes + 255) & ~(size_t)255; return o;
  };

  size_t oOut0   = alloc((size_t)N_*64*2);
  size_t oH0     = alloc((size_t)(N_+1)*64*2);   // +1 zeroed sentinel row
  size_t oH1     = alloc((size_t)(N_+1)*64*2);
  size_t oHq0    = alloc((size_t)(N_+1)*64);     // fp8 mirror of h0
  size_t oHq1    = alloc((size_t)(N_+1)*64);     // fp8 mirror of h1
  size_t oGated  = alloc((size_t)N_*12*4);
  size_t oBEdges = alloc((size_t)E_*4);
  size_t oSorted = alloc((size_t)E_*4 + 256);    // pad: phase-1 tail reads past end (masked)
  size_t oRS     = alloc((size_t)(nb+1)*NC*4);   // run starts, bin-major
  size_t oKptr   = alloc(((size_t)nb*160+2)*4);
  size_t oKperm  = alloc((size_t)nb*160);
  size_t oCanon  = alloc((size_t)CAN_TOT*2);
  size_t oCnt    = alloc((size_t)nb*4);
  size_t oGptr   = alloc((size_t)(G_+1)*4);
  size_t oFlag   = alloc(256);
  size_t oWall   = alloc((size_t)20480*2);
  size_t oWgru   = alloc((size_t)24576*2);
  size_t oWr1    = alloc((size_t)12288*2);
  size_t oWiw2   = alloc((size_t)1024*2);
  size_t oWjw2   = alloc((size_t)1024*2);

  bf16*  out0    = (bf16*)(ws + oOut0);
  bf16*  h0      = (bf16*)(ws + oH0);
  bf16*  h1      = (bf16*)(ws + oH1);
  unsigned char* hq0 = (unsigned char*)(ws + oHq0);
  unsigned char* hq1 = (unsigned char*)(ws + oHq1);
  float* gated   = (float*)(ws + oGated);
  unsigned int* bucketed = (unsigned int*)(ws + oBEdges);
  int*   sorted_src = (int*)(ws + oSorted);
  int*   rs      = (int*)(ws + oRS);
  int*   kptr    = (int*)(ws + oKptr);
  unsigned char* kperm = (unsigned char*)(ws + oKperm);
  bf16*  can     = (bf16*)(ws + oCanon);
  int*   bkt_cnt = (int*)(ws + oCnt);
  int*   gptr    = (int*)(ws + oGptr);
  int*   flag    = (int*)(ws + oFlag);
  unsigned short* wall  = (unsigned short*)(ws + oWall);
  unsigned short* wgru  = (unsigned short*)(ws + oWgru);
  unsigned short* wr1   = (unsigned short*)(ws + oWr1);
  unsigned short* wiw2s = (unsigned short*)(ws + oWiw2);
  unsigned short* wjw2s = (unsigned short*)(ws + oWjw2);

  const bf16* xC    = can + CAN_X;
  const bf16* l0wC  = can + CAN_L0W;
  const bf16* l0bC  = can + CAN_L0B;
  const bf16* eeC   = can + CAN_EE;
  const bf16* cbC   = can + CAN_CB;
  const bf16* wihC  = can + CAN_WIH;
  const bf16* whhC  = can + CAN_WHH;
  const bf16* bihC  = can + CAN_BIH;
  const bf16* bhhC  = can + CAN_BHH;
  const bf16* iw1C  = can + CAN_IW1;
  const bf16* ib1C  = can + CAN_IB1;
  const bf16* iw2C  = can + CAN_IW2;
  const bf16* ib2C  = can + CAN_IB2;
  const bf16* jw1C  = can + CAN_JW1;
  const bf16* jb1C  = can + CAN_JB1;
  const bf16* jw2C  = can + CAN_JW2;
  const bf16* jb2C  = can + CAN_JB2;

  PtrPack pk;
  pk.p[0]=d_in[0];  pk.p[1]=d_in[4];  pk.p[2]=d_in[5];  pk.p[3]=d_in[6];
  pk.p[4]=d_in[7];  pk.p[5]=d_in[8];  pk.p[6]=d_in[9];  pk.p[7]=d_in[10];
  pk.p[8]=d_in[11]; pk.p[9]=d_in[12]; pk.p[10]=d_in[13]; pk.p[11]=d_in[14];
  pk.p[12]=d_in[15]; pk.p[13]=d_in[16]; pk.p[14]=d_in[17]; pk.p[15]=d_in[18];
  pk.p[16]=d_in[19];

  const int gNw  = (N_+63)/64;       // 64 nodes / block (readout)

  // --- setup (sniff + workspace zeroing fused) ---
  k_sniff<<<3, 256, 0, stream>>>((const unsigned int*)d_in[0], flag,
                                 bkt_cnt, nb,
                                 (int*)(ws + oH0 + (size_t)N_*128),
                                 (int*)(ws + oH1 + (size_t)N_*128),
                                 (int*)(ws + oHq0 + (size_t)N_*64),
                                 (int*)(ws + oHq1 + (size_t)N_*64));
  k_canon<<<(CAN_TOT+255)/256, 256, 0, stream>>>(pk, flag, can);
  k_csort<<<NC, 512, 0, stream>>>(ei, ei + E_, ea, E_, nb, NC, bucketed, rs, bkt_cnt);
  k_bsort2<<<nb, 256, 0, stream>>>(bucketed, rs, NC, bkt_cnt, nb, E_, kptr, sorted_src, kperm);
  k_lin0<<<(N_*64+255)/256, 256, 0, stream>>>(xC, l0wC, l0bC, out0, h0, hq0, N_);
  k_prep<<<32, 256, 0, stream>>>(eeC, wihC, whhC, iw1C, jw1C, iw2C, jw2C,
                                 wall, wgru, wr1, wiw2s, wjw2s, batch, N_, G_, gptr);

  // --- 6 propagation steps (double-buffered h + fp8 mirror) ---
  bf16* hb[2] = {h0, h1};
  unsigned char* hqb[2] = {hq0, hq1};
  for (int step = 0; step < 6; ++step){
    k_step<<<nbs, 256, 0, stream>>>(hb[step&1], hb[(step+1)&1],
                                    hqb[step&1], hqb[(step+1)&1],
                                    sorted_src, kptr, kperm,
                                    wall, wgru, cbC, bihC, bhhC, N_);
  }
  bf16* hfin = hb[0];   // after 6 steps

  // --- readout + graph sum ---
  k_read<<<gNw, 256, 0, stream>>>(hfin, out0, wr1, ib1C, jb1C, wiw2s, wjw2s,
                                  ib2C, jb2C, gated, N_);
  k_graphsum<<<G_, 256, 0, stream>>>(gated, gptr, flag, d_out);
}